// Round 7
// baseline (235.735 us; speedup 1.0000x reference)
//
#include <hip/hip_runtime.h>
#include <math.h>

// Problem constants
#define BB 2
#define LL 512
#define HH 768
#define EE 512
#define RR 32768
#define H2 384
#define MM 1024   // B*E entity rows

typedef __attribute__((ext_vector_type(8))) short     bf16x8;  // MFMA A/B frag
typedef __attribute__((ext_vector_type(4))) float     f32x4;   // MFMA C/D frag
typedef __attribute__((ext_vector_type(8))) unsigned short u16x8;

#define BUFE (64 * 72)    // one LDS buffer: 64 rows x (64+8) bf16

__device__ __forceinline__ unsigned short f2bf(float f) {
    unsigned int u = __float_as_uint(f);
    u = (u + 0x7FFFu + ((u >> 16) & 1u)) >> 16;   // round-to-nearest-even
    return (unsigned short)u;
}

// ---------------------------------------------------------------------------
// 32x32 weight transpose tile: [K][N] fp32 -> [N][K] bf16. T = 32*40 ushorts.
// ---------------------------------------------------------------------------
__device__ __forceinline__ void wtrans(const float* __restrict__ src,
                                       unsigned short* __restrict__ dst,
                                       int K, int N, int tile, unsigned short* T)
{
    const int t = threadIdx.x;
    const int tn = N >> 5;
    const int n0 = (tile % tn) * 32;
    const int k0 = (tile / tn) * 32;
    const int r  = t >> 3;           // 0..31 (k within tile)
    const int c4 = (t & 7) * 4;      // 0..28 (n within tile)
    const float4 g = *(const float4*)(src + (size_t)(k0 + r) * N + n0 + c4);
    T[(c4 + 0) * 40 + r] = f2bf(g.x);
    T[(c4 + 1) * 40 + r] = f2bf(g.y);
    T[(c4 + 2) * 40 + r] = f2bf(g.z);
    T[(c4 + 3) * 40 + r] = f2bf(g.w);
    __syncthreads();
    const int n  = t >> 3;           // 0..31
    const int k4 = (t & 7) * 4;      // 0..28
    *(ushort4*)(dst + (size_t)(n0 + n) * K + k0 + k4) = *(ushort4*)&T[n * 40 + k4];
}

// ---------------------------------------------------------------------------
// prep:
//   [0,576)     W1 head top-half transpose -> W1ht
//   [576,1152)  W1 tail top-half transpose -> W1tt
//   [1152,2176) gather hidden[b, ent_start] -> Hbf bf16 [1024][768]
//   [2176,2200) embc[l][n] = b1[n] + sum_k emb[l][k]*W1[768+k][n]
//   2200        zero hlin/tlin accumulators + out[0]
// ---------------------------------------------------------------------------
__global__ __launch_bounds__(256) void prep(
    const float* __restrict__ hW1, const float* __restrict__ tW1,
    unsigned short* __restrict__ W1ht, unsigned short* __restrict__ W1tt,
    const float* __restrict__ hidden, const int* __restrict__ ent_start,
    const float* __restrict__ emb,
    const float* __restrict__ hb1, const float* __restrict__ tb1,
    unsigned short* __restrict__ Hbf, float* __restrict__ embc,
    float* __restrict__ hlin, float* __restrict__ tlin, float* __restrict__ out)
{
    __shared__ unsigned short T[32 * 40];
    __shared__ float red[4][192];
    const int bid = blockIdx.x;
    const int t = threadIdx.x;

    if (bid == 2200) {
        const float4 z = {0.f, 0.f, 0.f, 0.f};
        ((float4*)hlin)[t] = z; ((float4*)hlin)[256 + t] = z;
        ((float4*)tlin)[t] = z; ((float4*)tlin)[256 + t] = z;
        if (t == 0) out[0] = 0.f;
        return;
    }

    if (bid >= 2176) {
        // ---- embc: per-(label, col) folded bias table
        const int eb = bid - 2176;           // 0..23
        const int tc = t & 63;
        const int kg = t >> 6;               // 0..3 k-group
        const int n = eb * 64 + tc;          // global col 0..1535
        const float* W = (n < 768) ? hW1 : tW1;
        const int cc = (n < 768) ? n : n - 768;
        float a0 = 0.f, a1 = 0.f, a2 = 0.f;
        const int kbeg = kg * 192;
        #pragma unroll 8
        for (int k = kbeg; k < kbeg + 192; ++k) {
            const float w = W[(size_t)(768 + k) * 768 + cc];
            a0 += emb[k] * w;
            a1 += emb[768 + k] * w;
            a2 += emb[1536 + k] * w;
        }
        red[kg][0 * 64 + tc] = a0;
        red[kg][1 * 64 + tc] = a1;
        red[kg][2 * 64 + tc] = a2;
        __syncthreads();
        if (kg == 0) {
            const float b = (n < 768) ? hb1[n] : tb1[n - 768];
            #pragma unroll
            for (int l = 0; l < 3; ++l) {
                embc[l * 1536 + n] = b + red[0][l * 64 + tc] + red[1][l * 64 + tc]
                                       + red[2][l * 64 + tc] + red[3][l * 64 + tc];
            }
        }
        return;
    }

    if (bid >= 1152) {
        // ---- gather hidden[b, ent_start[m]] as bf16 (768 cols)
        const int m = bid - 1152;            // 0..1023
        if (t >= 96) return;
        const int b = m >> 9;
        const int idx = ent_start[m];
        const float4* s = (const float4*)(hidden + (size_t)(b * LL + idx) * HH);
        const float4 v0 = s[2 * t];
        const float4 v1 = s[2 * t + 1];
        u16x8 o;
        o[0] = f2bf(v0.x); o[1] = f2bf(v0.y); o[2] = f2bf(v0.z); o[3] = f2bf(v0.w);
        o[4] = f2bf(v1.x); o[5] = f2bf(v1.y); o[6] = f2bf(v1.z); o[7] = f2bf(v1.w);
        *(u16x8*)(Hbf + (size_t)m * 768 + 8 * t) = o;
        return;
    }

    // ---- W1 transposes (top halves only; bottom folded into embc)
    if (bid < 576) wtrans(hW1, W1ht, 768, 768, bid, T);
    else           wtrans(tW1, W1tt, 768, 768, bid - 576, T);
}

// ---------------------------------------------------------------------------
// bf16 MFMA GEMM body. 64x64 tile, 256 threads (4 waves, 2x2), 16x16x32 MFMA.
// K_STEP=64, double-buffered LDS, ONE raw s_barrier per K-step, 2-deep
// register prefetch (counted vmcnt at ds_write). NT = K/64 even.
// ---------------------------------------------------------------------------
template<bool RELU, bool BIAS, bool EB, bool WBF16, bool LIN>
__device__ __forceinline__ void gemm_body(
    int tile, int nx,
    const unsigned short* __restrict__ A, int lda, int aoff1,
    const unsigned short* __restrict__ Bt0, const unsigned short* __restrict__ Bt1,
    int ldb, int Nh,
    const float* __restrict__ bias0, const float* __restrict__ bias1,
    const float* __restrict__ embc, const int* __restrict__ labels,
    const float* __restrict__ linW, float* __restrict__ hlin, float* __restrict__ tlin,
    int K, unsigned short* __restrict__ Cb, int ldc,
    unsigned short* As, unsigned short* Bs)
{
    const int tid = threadIdx.x;
    const int n0 = (tile % nx) * 64;
    const int m0 = (tile / nx) * 64;
    const int hf = (n0 >= Nh) ? 1 : 0;
    const unsigned short* Bt = hf ? Bt1 : Bt0;
    const int nc0 = n0 - (hf ? Nh : 0);
    const int aoff = hf ? aoff1 : 0;

    // staging: thread t covers row sr, 16 bf16 at k-offset sk (2 x u16x8)
    const int sr = tid >> 2;            // 0..63
    const int sk = (tid & 3) * 16;      // 0,16,32,48

    const unsigned short* Ap = A + (size_t)(m0 + sr) * lda + aoff + sk;
    const unsigned short* Bp = Bt + (size_t)(nc0 + sr) * ldb + sk;

    const int lane = tid & 63;
    const int wave = tid >> 6;
    const int wm = (wave & 1) * 32;
    const int wn = (wave >> 1) * 32;
    const int l15 = lane & 15;
    const int quad = lane >> 4;
    const int swo = sr * 72 + sk;
    const int aro = quad * 8;

    f32x4 acc00 = {}, acc01 = {}, acc10 = {}, acc11 = {};

    // two register stage-sets (2-deep prefetch)
    u16x8 pa0, pa1, pb0, pb1;           // even K-steps
    u16x8 qa0, qa1, qb0, qb1;           // odd K-steps

#define GLOADP(ko) { pa0 = *(const u16x8*)(Ap + (ko)); pa1 = *(const u16x8*)(Ap + (ko) + 8); \
                     pb0 = *(const u16x8*)(Bp + (ko)); pb1 = *(const u16x8*)(Bp + (ko) + 8); }
#define GLOADQ(ko) { qa0 = *(const u16x8*)(Ap + (ko)); qa1 = *(const u16x8*)(Ap + (ko) + 8); \
                     qb0 = *(const u16x8*)(Bp + (ko)); qb1 = *(const u16x8*)(Bp + (ko) + 8); }
#define SWRITEP(bi) { unsigned short* Aw = As + (bi) * BUFE; unsigned short* Bw = Bs + (bi) * BUFE; \
                      *(u16x8*)&Aw[swo] = pa0; *(u16x8*)&Aw[swo + 8] = pa1; \
                      *(u16x8*)&Bw[swo] = pb0; *(u16x8*)&Bw[swo + 8] = pb1; }
#define SWRITEQ(bi) { unsigned short* Aw = As + (bi) * BUFE; unsigned short* Bw = Bs + (bi) * BUFE; \
                      *(u16x8*)&Aw[swo] = qa0; *(u16x8*)&Aw[swo + 8] = qa1; \
                      *(u16x8*)&Bw[swo] = qb0; *(u16x8*)&Bw[swo + 8] = qb1; }
#define BAR() { asm volatile("s_waitcnt lgkmcnt(0)" ::: "memory"); \
                __builtin_amdgcn_s_barrier(); \
                __builtin_amdgcn_sched_barrier(0); }
#define MFMA8(bi) { const unsigned short* Ac = As + (bi) * BUFE; \
                    const unsigned short* Bc = Bs + (bi) * BUFE; \
        const bf16x8 fa0 = *(const bf16x8*)&Ac[(wm + l15) * 72 + aro]; \
        const bf16x8 fa1 = *(const bf16x8*)&Ac[(wm + 16 + l15) * 72 + aro]; \
        const bf16x8 fb0 = *(const bf16x8*)&Bc[(wn + l15) * 72 + aro]; \
        const bf16x8 fb1 = *(const bf16x8*)&Bc[(wn + 16 + l15) * 72 + aro]; \
        const bf16x8 ga0 = *(const bf16x8*)&Ac[(wm + l15) * 72 + aro + 32]; \
        const bf16x8 ga1 = *(const bf16x8*)&Ac[(wm + 16 + l15) * 72 + aro + 32]; \
        const bf16x8 gb0 = *(const bf16x8*)&Bc[(wn + l15) * 72 + aro + 32]; \
        const bf16x8 gb1 = *(const bf16x8*)&Bc[(wn + 16 + l15) * 72 + aro + 32]; \
        acc00 = __builtin_amdgcn_mfma_f32_16x16x32_bf16(fa0, fb0, acc00, 0, 0, 0); \
        acc01 = __builtin_amdgcn_mfma_f32_16x16x32_bf16(fa0, fb1, acc01, 0, 0, 0); \
        acc10 = __builtin_amdgcn_mfma_f32_16x16x32_bf16(fa1, fb0, acc10, 0, 0, 0); \
        acc11 = __builtin_amdgcn_mfma_f32_16x16x32_bf16(fa1, fb1, acc11, 0, 0, 0); \
        acc00 = __builtin_amdgcn_mfma_f32_16x16x32_bf16(ga0, gb0, acc00, 0, 0, 0); \
        acc01 = __builtin_amdgcn_mfma_f32_16x16x32_bf16(ga0, gb1, acc01, 0, 0, 0); \
        acc10 = __builtin_amdgcn_mfma_f32_16x16x32_bf16(ga1, gb0, acc10, 0, 0, 0); \
        acc11 = __builtin_amdgcn_mfma_f32_16x16x32_bf16(ga1, gb1, acc11, 0, 0, 0); }

    const int NT = K >> 6;              // even (6 or 12)

    GLOADP(0);
    GLOADQ(64);
    SWRITEP(0);

    for (int it = 0; it < NT; it += 2) {
        BAR();
        if (it + 2 < NT) GLOADP((it + 2) << 6);
        MFMA8(0);
        SWRITEQ(1);                      // counted vmcnt: waits K(it+1) only
        BAR();
        if (it + 3 < NT) GLOADQ((it + 3) << 6);
        MFMA8(1);
        if (it + 2 < NT) SWRITEP(0);     // counted vmcnt: waits K(it+2) only
    }

#undef GLOADP
#undef GLOADQ
#undef SWRITEP
#undef SWRITEQ
#undef BAR
#undef MFMA8

    // epilogue: C/D layout col=lane&15, row=quad*4+reg
    float bias_v0 = 0.f, bias_v1 = 0.f;
    if (BIAS) {
        const float* bb = hf ? bias1 : bias0;
        bias_v0 = bb[nc0 + wn + l15];
        bias_v1 = bb[nc0 + wn + 16 + l15];
    }
    const int col0 = n0 + wn + l15;
    const int col1 = col0 + 16;
    float2 lw0 = {0.f, 0.f}, lw1 = {0.f, 0.f};
    float* lout = nullptr;
    if (LIN) {
        lw0 = ((const float2*)linW)[col0];
        lw1 = ((const float2*)linW)[col1];
        lout = hf ? tlin : hlin;
    }
    const f32x4 accs[2][2] = {{acc00, acc01}, {acc10, acc11}};
    #pragma unroll
    for (int mi = 0; mi < 2; ++mi) {
        #pragma unroll
        for (int r = 0; r < 4; ++r) {
            const int row = m0 + wm + mi * 16 + quad * 4 + r;
            float v0 = accs[mi][0][r];
            float v1 = accs[mi][1][r];
            if (BIAS) { v0 += bias_v0; v1 += bias_v1; }
            if (EB) {
                const int lab = labels[row];
                v0 += embc[lab * 1536 + col0];
                v1 += embc[lab * 1536 + col1];
            }
            if (RELU) { v0 = fmaxf(v0, 0.f); v1 = fmaxf(v1, 0.f); }
            if (WBF16) {
                Cb[(size_t)row * ldc + col0] = f2bf(v0);
                Cb[(size_t)row * ldc + col1] = f2bf(v1);
            }
            if (LIN) {
                float s0 = v0 * lw0.x + v1 * lw1.x;
                float s1 = v0 * lw0.y + v1 * lw1.y;
                #pragma unroll
                for (int o = 8; o >= 1; o >>= 1) {
                    s0 += __shfl_xor(s0, o, 64);
                    s1 += __shfl_xor(s1, o, 64);
                }
                if (l15 == 0) {
                    atomicAdd(&lout[2 * row],     s0);
                    atomicAdd(&lout[2 * row + 1], s1);
                }
            }
        }
    }
}

// Generic GEMM kernel (stages 3-4), 2-D grid.
template<bool RELU, bool BIAS, bool EB, bool WBF16, bool LIN>
__global__ __launch_bounds__(256) void gemm_mfma(
    const unsigned short* __restrict__ A, int lda, int aoff1,
    const unsigned short* __restrict__ Bt0, const unsigned short* __restrict__ Bt1,
    int ldb, int Nh,
    const float* __restrict__ bias0, const float* __restrict__ bias1,
    const float* __restrict__ embc, const int* __restrict__ labels,
    const float* __restrict__ linW, float* __restrict__ hlin, float* __restrict__ tlin,
    int K, unsigned short* __restrict__ Cb, int ldc)
{
    __shared__ __align__(16) unsigned short As[2 * BUFE];
    __shared__ __align__(16) unsigned short Bs[2 * BUFE];
    gemm_body<RELU, BIAS, EB, WBF16, LIN>(
        blockIdx.y * gridDim.x + blockIdx.x, gridDim.x,
        A, lda, aoff1, Bt0, Bt1, ldb, Nh,
        bias0, bias1, embc, labels, linW, hlin, tlin,
        K, Cb, ldc, As, Bs);
}

// ---------------------------------------------------------------------------
// gemm1 + overlapped W2/bil transposes: blocks [0,384) = layer1 tiles,
// blocks [384,1248) = weight transposes consumed only by later launches.
// ---------------------------------------------------------------------------
__global__ __launch_bounds__(256) void gemm1_plus(
    const unsigned short* __restrict__ Hbf,
    const unsigned short* __restrict__ W1ht, const unsigned short* __restrict__ W1tt,
    const float* __restrict__ embc, const int* __restrict__ ent_label,
    unsigned short* __restrict__ Y1bf,
    const float* __restrict__ hW2, const float* __restrict__ tW2,
    const float* __restrict__ bilW,
    unsigned short* __restrict__ W2ht, unsigned short* __restrict__ W2tt,
    unsigned short* __restrict__ bW0t, unsigned short* __restrict__ bW1t)
{
    __shared__ __align__(16) unsigned short As[2 * BUFE];
    __shared__ __align__(16) unsigned short Bs[2 * BUFE];
    const int bid = blockIdx.x;
    if (bid >= 384) {
        const int task = bid - 384;
        if (task < 288)      wtrans(hW2, W2ht, 768, 384, task, As);
        else if (task < 576) wtrans(tW2, W2tt, 768, 384, task - 288, As);
        else if (task < 720) wtrans(bilW, bW0t, 384, 384, task - 576, As);
        else                 wtrans(bilW + 384 * 384, bW1t, 384, 384, task - 720, As);
        return;
    }
    gemm_body<true, false, true, true, false>(
        bid, 24, Hbf, 768, 0, W1ht, W1tt, 768, 768,
        nullptr, nullptr, embc, ent_label, nullptr, nullptr, nullptr,
        768, Y1bf, 1536, As, Bs);
}

// ---------------------------------------------------------------------------
// Fused score+gather+CE: one block per (m-block 64, t-block 32) tile.
// Phase-split K-loop: steps 0-5 accumulate o=0 (hW cols 0..383), steps 6-11
// accumulate o=1 (hW cols 384..767); identical B (tails) both phases.
// Scores parked in LDS; block scans the relation list (L2-resident) and
// processes relations in its tile: logits + CE partial + one atomicAdd.
// ---------------------------------------------------------------------------
__global__ __launch_bounds__(256) void score_rel(
    const unsigned short* __restrict__ hWbf, const unsigned short* __restrict__ HTbf,
    const float* __restrict__ hlin, const float* __restrict__ tlin,
    const float* __restrict__ lin_b,
    const int* __restrict__ rel_head, const int* __restrict__ rel_tail,
    const int* __restrict__ rel_label,
    float* __restrict__ out)
{
    __shared__ __align__(16) unsigned short As[2][64 * 72];   // 18432 B
    __shared__ __align__(16) unsigned short Bs[2][32 * 72];   //  9216 B
    __shared__ float wsum[4];

    const int tid = threadIdx.x;
    const int t0 = blockIdx.x * 32;      // tail-col block (0..480)
    const int m0 = blockIdx.y * 64;      // mh row block (0..960)
    const int batch = m0 >> 9;

    // A staging: 64 rows x 64 k per step (2 x u16x8 per thread)
    const int asr = tid >> 2;            // 0..63
    const int ask = (tid & 3) * 16;      // 0,16,32,48
    const unsigned short* Ap = hWbf + (size_t)(m0 + asr) * 768 + ask;
    // B staging: 32 rows x 64 k per step (1 x u16x8 per thread)
    const int bsr = tid >> 3;            // 0..31
    const int bsk = (tid & 7) * 8;       // 0..56
    const unsigned short* Bp = HTbf + (size_t)(batch * 512 + t0 + bsr) * 768 + 384 + bsk;

    const int lane = tid & 63;
    const int wave = tid >> 6;
    const int wm = (wave & 1) * 32;      // 2 m-waves
    const int wn = (wave >> 1) * 16;     // 2 n-waves x 16 cols
    const int l15 = lane & 15;
    const int quad = lane >> 4;
    const int aro = quad * 8;

    f32x4 p00 = {}, p01 = {};            // o=0: m-frag 0/1
    f32x4 p10 = {}, p11 = {};            // o=1

    for (int it = 0; it < 12; ++it) {
        const int koA = (it < 6) ? it * 64 : (it - 6) * 64 + 384;
        const int koB = ((it < 6) ? it : it - 6) * 64;
        const u16x8 av0 = *(const u16x8*)(Ap + koA);
        const u16x8 av1 = *(const u16x8*)(Ap + koA + 8);
        const u16x8 bv  = *(const u16x8*)(Bp + koB);
        __syncthreads();
        *(u16x8*)&As[it & 1][asr * 72 + ask]     = av0;
        *(u16x8*)&As[it & 1][asr * 72 + ask + 8] = av1;
        *(u16x8*)&Bs[it & 1][bsr * 72 + bsk]     = bv;
        __syncthreads();
        const unsigned short* Ac = As[it & 1];
        const unsigned short* Bc = Bs[it & 1];
        const bf16x8 fa0 = *(const bf16x8*)&Ac[(wm + l15) * 72 + aro];
        const bf16x8 fa1 = *(const bf16x8*)&Ac[(wm + 16 + l15) * 72 + aro];
        const bf16x8 fb  = *(const bf16x8*)&Bc[(wn + l15) * 72 + aro];
        const bf16x8 ga0 = *(const bf16x8*)&Ac[(wm + l15) * 72 + aro + 32];
        const bf16x8 ga1 = *(const bf16x8*)&Ac[(wm + 16 + l15) * 72 + aro + 32];
        const bf16x8 gb  = *(const bf16x8*)&Bc[(wn + l15) * 72 + aro + 32];
        if (it < 6) {
            p00 = __builtin_amdgcn_mfma_f32_16x16x32_bf16(fa0, fb, p00, 0, 0, 0);
            p01 = __builtin_amdgcn_mfma_f32_16x16x32_bf16(fa1, fb, p01, 0, 0, 0);
            p00 = __builtin_amdgcn_mfma_f32_16x16x32_bf16(ga0, gb, p00, 0, 0, 0);
            p01 = __builtin_amdgcn_mfma_f32_16x16x32_bf16(ga1, gb, p01, 0, 0, 0);
        } else {
            p10 = __builtin_amdgcn_mfma_f32_16x16x32_bf16(fa0, fb, p10, 0, 0, 0);
            p11 = __builtin_amdgcn_mfma_f32_16x16x32_bf16(fa1, fb, p11, 0, 0, 0);
            p10 = __builtin_amdgcn_mfma_f32_16x16x32_bf16(ga0, gb, p10, 0, 0, 0);
            p11 = __builtin_amdgcn_mfma_f32_16x16x32_bf16(ga1, gb, p11, 0, 0, 0);
        }
    }

    // park scores in LDS (alias over As): 2 planes of [64][33] fp32 = 16896 B
    __syncthreads();                     // all waves done reading As/Bs
    float* Sl = (float*)&As[0][0];
    const int col = wn + l15;            // 0..31
    #pragma unroll
    for (int mi = 0; mi < 2; ++mi) {
        #pragma unroll
        for (int r = 0; r < 4; ++r) {
            const int row = wm + mi * 16 + quad * 4 + r;
            Sl[row * 33 + col]           = mi ? p01[r] : p00[r];
            Sl[64 * 33 + row * 33 + col] = mi ? p11[r] : p10[r];
        }
    }
    __syncthreads();

    // scan all relations; process those in this tile (exactly-once cover)
    const float lb0 = lin_b[0], lb1 = lin_b[1];
    float ce = 0.f;
    for (int j = tid; j < BB * RR; j += 256) {
        const int boff = (j >> 15) << 9;
        const int mh = boff + rel_head[j];
        if ((unsigned)(mh - m0) < 64u) {
            const int t = rel_tail[j];
            if ((unsigned)(t - t0) < 32u) {
                const int mt = boff + t;
                const float2 hl = ((const float2*)hlin)[mh];
                const float2 tl = ((const float2*)tlin)[mt];
                const int so = (mh - m0) * 33 + (t - t0);
                const float z0 = Sl[so]           + hl.x + tl.x + lb0;
                const float z1 = Sl[64 * 33 + so] + hl.y + tl.y + lb1;
                out[1 + 2 * (size_t)j] = z0;
                out[2 + 2 * (size_t)j] = z1;
                const float mx = fmaxf(z0, z1);
                const float mn = fminf(z0, z1);
                ce += mx + log1pf(expf(mn - mx)) - (rel_label[j] ? z1 : z0);
            }
        }
    }
    #pragma unroll
    for (int o = 32; o >= 1; o >>= 1) ce += __shfl_xor(ce, o, 64);
    if (lane == 0) wsum[wave] = ce;
    __syncthreads();
    if (tid == 0)
        atomicAdd(out, (wsum[0] + wsum[1] + wsum[2] + wsum[3]) * (1.0f / (float)RR));
}

// ---------------------------------------------------------------------------
extern "C" void kernel_launch(void* const* d_in, const int* in_sizes, int n_in,
                              void* d_out, int out_size, void* d_ws, size_t ws_size,
                              hipStream_t stream) {
    const float* hidden    = (const float*)d_in[0];
    const int*   ent_start = (const int*)d_in[1];
    const int*   ent_label = (const int*)d_in[2];
    const int*   rel_head  = (const int*)d_in[3];
    const int*   rel_tail  = (const int*)d_in[4];
    const int*   rel_label = (const int*)d_in[5];
    const float* emb       = (const float*)d_in[6];
    const float* head_W1   = (const float*)d_in[7];
    const float* head_b1   = (const float*)d_in[8];
    const float* head_W2   = (const float*)d_in[9];
    const float* head_b2   = (const float*)d_in[10];
    const float* tail_W1   = (const float*)d_in[11];
    const float* tail_b1   = (const float*)d_in[12];
    const float* tail_W2   = (const float*)d_in[13];
    const float* tail_b2   = (const float*)d_in[14];
    const float* bil_W     = (const float*)d_in[15];
    const float* lin_W     = (const float*)d_in[16];
    const float* lin_b     = (const float*)d_in[17];
    float* out = (float*)d_out;

    // Workspace carve-up (256B-aligned chunks)
    char* w = (char*)d_ws;
    auto carve = [&](size_t bytes) {
        char* p = w; w += (bytes + 255) & ~(size_t)255; return p;
    };
    unsigned short* Hbf  = (unsigned short*)carve((size_t)MM * 768 * 2);
    unsigned short* Y1bf = (unsigned short*)carve((size_t)MM * 1536 * 2);
    unsigned short* HTbf = (unsigned short*)carve((size_t)MM * 768 * 2);
    unsigned short* hWbf = (unsigned short*)carve((size_t)MM * 768 * 2);
    unsigned short* W1ht = (unsigned short*)carve((size_t)768 * 768 * 2);
    unsigned short* W1tt = (unsigned short*)carve((size_t)768 * 768 * 2);
    unsigned short* W2ht = (unsigned short*)carve((size_t)384 * 768 * 2);
    unsigned short* W2tt = (unsigned short*)carve((size_t)384 * 768 * 2);
    unsigned short* bW0t = (unsigned short*)carve((size_t)384 * 384 * 2);
    unsigned short* bW1t = (unsigned short*)carve((size_t)384 * 384 * 2);
    float*          embc = (float*)carve((size_t)3 * 1536 * 4);
    float*          hlin = (float*)carve(2048 * 4);
    float*          tlin = (float*)carve(2048 * 4);

    // 1) W1 transpose + hidden gather + embc fold + zeroing
    prep<<<2201, 256, 0, stream>>>(
        head_W1, tail_W1, W1ht, W1tt,
        hidden, ent_start, emb, head_b1, tail_b1, Hbf, embc,
        hlin, tlin, out);

    // 2) layer1 (384 tiles) + overlapped W2/bil transposes (864 blocks)
    gemm1_plus<<<1248, 256, 0, stream>>>(
        Hbf, W1ht, W1tt, embc, ent_label, Y1bf,
        head_W2, tail_W2, bil_W, W2ht, W2tt, bW0t, bW1t);

    // 3) layer2: HTbf = relu(Y1 @ [W2h|W2t] + b2), N=768 (Nh=384), K=768,
    //    tail half reads Y1 cols 768..; epilogue fuses lin_proj via atomics
    gemm_mfma<true, true, false, true, true>
        <<<dim3(12, 16), 256, 0, stream>>>(
        Y1bf, 1536, 768, W2ht, W2tt, 768, 384, head_b2, tail_b2,
        nullptr, nullptr, lin_W, hlin, tlin, 768, HTbf, 768);

    // 4) bilinear left product: hWbf = heads @ bil_W[o], N=768 (Nh=384), K=384
    gemm_mfma<false, false, false, true, false>
        <<<dim3(12, 16), 256, 0, stream>>>(
        HTbf, 768, 0, bW0t, bW1t, 384, 384, nullptr, nullptr,
        nullptr, nullptr, nullptr, nullptr, nullptr, 384, hWbf, 768);

    // 5) fused score + relation gather + CE
    score_rel<<<dim3(16, 16), 256, 0, stream>>>(
        hWbf, HTbf, hlin, tlin, lin_b,
        rel_head, rel_tail, rel_label, out);
}

// Round 8
// 163.397 us; speedup vs baseline: 1.4427x; 1.4427x over previous
//
#include <hip/hip_runtime.h>
#include <math.h>

// Problem constants
#define BB 2
#define LL 512
#define HH 768
#define EE 512
#define RR 32768
#define H2 384
#define MM 1024   // B*E entity rows

typedef __attribute__((ext_vector_type(8))) short     bf16x8;  // MFMA A/B frag
typedef __attribute__((ext_vector_type(4))) float     f32x4;   // MFMA C/D frag
typedef __attribute__((ext_vector_type(8))) unsigned short u16x8;

#define BUFE (64 * 72)    // one LDS buffer: 64 rows x (64+8) bf16

__device__ __forceinline__ unsigned short f2bf(float f) {
    unsigned int u = __float_as_uint(f);
    u = (u + 0x7FFFu + ((u >> 16) & 1u)) >> 16;   // round-to-nearest-even
    return (unsigned short)u;
}

// ---------------------------------------------------------------------------
// 32x32 weight transpose tile: [K][N] fp32 -> [N][K] bf16. T = 32*40 ushorts.
// ---------------------------------------------------------------------------
__device__ __forceinline__ void wtrans(const float* __restrict__ src,
                                       unsigned short* __restrict__ dst,
                                       int K, int N, int tile, unsigned short* T)
{
    const int t = threadIdx.x;
    const int tn = N >> 5;
    const int n0 = (tile % tn) * 32;
    const int k0 = (tile / tn) * 32;
    const int r  = t >> 3;           // 0..31 (k within tile)
    const int c4 = (t & 7) * 4;      // 0..28 (n within tile)
    const float4 g = *(const float4*)(src + (size_t)(k0 + r) * N + n0 + c4);
    T[(c4 + 0) * 40 + r] = f2bf(g.x);
    T[(c4 + 1) * 40 + r] = f2bf(g.y);
    T[(c4 + 2) * 40 + r] = f2bf(g.z);
    T[(c4 + 3) * 40 + r] = f2bf(g.w);
    __syncthreads();
    const int n  = t >> 3;           // 0..31
    const int k4 = (t & 7) * 4;      // 0..28
    *(ushort4*)(dst + (size_t)(n0 + n) * K + k0 + k4) = *(ushort4*)&T[n * 40 + k4];
}

// ---------------------------------------------------------------------------
// prep:
//   [0,576)     W1 head top-half transpose -> W1ht
//   [576,1152)  W1 tail top-half transpose -> W1tt
//   [1152,2176) gather hidden[b, ent_start] -> Hbf bf16 [1024][768]
//   [2176,2200) embc[l][n] = b1[n] + sum_k emb[l][k]*W1[768+k][n]
//   2200        zero hlin/tlin accumulators + out[0] + bin counts
// ---------------------------------------------------------------------------
__global__ __launch_bounds__(256) void prep(
    const float* __restrict__ hW1, const float* __restrict__ tW1,
    unsigned short* __restrict__ W1ht, unsigned short* __restrict__ W1tt,
    const float* __restrict__ hidden, const int* __restrict__ ent_start,
    const float* __restrict__ emb,
    const float* __restrict__ hb1, const float* __restrict__ tb1,
    unsigned short* __restrict__ Hbf, float* __restrict__ embc,
    float* __restrict__ hlin, float* __restrict__ tlin,
    int* __restrict__ counts, float* __restrict__ out)
{
    __shared__ unsigned short T[32 * 40];
    __shared__ float red[4][192];
    const int bid = blockIdx.x;
    const int t = threadIdx.x;

    if (bid == 2200) {
        const float4 z = {0.f, 0.f, 0.f, 0.f};
        ((float4*)hlin)[t] = z; ((float4*)hlin)[256 + t] = z;
        ((float4*)tlin)[t] = z; ((float4*)tlin)[256 + t] = z;
        counts[t] = 0;                       // 256 tile-bin counters
        if (t == 0) out[0] = 0.f;
        return;
    }

    if (bid >= 2176) {
        // ---- embc: per-(label, col) folded bias table
        const int eb = bid - 2176;           // 0..23
        const int tc = t & 63;
        const int kg = t >> 6;               // 0..3 k-group
        const int n = eb * 64 + tc;          // global col 0..1535
        const float* W = (n < 768) ? hW1 : tW1;
        const int cc = (n < 768) ? n : n - 768;
        float a0 = 0.f, a1 = 0.f, a2 = 0.f;
        const int kbeg = kg * 192;
        #pragma unroll 8
        for (int k = kbeg; k < kbeg + 192; ++k) {
            const float w = W[(size_t)(768 + k) * 768 + cc];
            a0 += emb[k] * w;
            a1 += emb[768 + k] * w;
            a2 += emb[1536 + k] * w;
        }
        red[kg][0 * 64 + tc] = a0;
        red[kg][1 * 64 + tc] = a1;
        red[kg][2 * 64 + tc] = a2;
        __syncthreads();
        if (kg == 0) {
            const float b = (n < 768) ? hb1[n] : tb1[n - 768];
            #pragma unroll
            for (int l = 0; l < 3; ++l) {
                embc[l * 1536 + n] = b + red[0][l * 64 + tc] + red[1][l * 64 + tc]
                                       + red[2][l * 64 + tc] + red[3][l * 64 + tc];
            }
        }
        return;
    }

    if (bid >= 1152) {
        // ---- gather hidden[b, ent_start[m]] as bf16 (768 cols)
        const int m = bid - 1152;            // 0..1023
        if (t >= 96) return;
        const int b = m >> 9;
        const int idx = ent_start[m];
        const float4* s = (const float4*)(hidden + (size_t)(b * LL + idx) * HH);
        const float4 v0 = s[2 * t];
        const float4 v1 = s[2 * t + 1];
        u16x8 o;
        o[0] = f2bf(v0.x); o[1] = f2bf(v0.y); o[2] = f2bf(v0.z); o[3] = f2bf(v0.w);
        o[4] = f2bf(v1.x); o[5] = f2bf(v1.y); o[6] = f2bf(v1.z); o[7] = f2bf(v1.w);
        *(u16x8*)(Hbf + (size_t)m * 768 + 8 * t) = o;
        return;
    }

    // ---- W1 transposes (top halves only; bottom folded into embc)
    if (bid < 576) wtrans(hW1, W1ht, 768, 768, bid, T);
    else           wtrans(tW1, W1tt, 768, 768, bid - 576, T);
}

// ---------------------------------------------------------------------------
// bf16 MFMA GEMM body. 64x64 tile, 256 threads (4 waves, 2x2), 16x16x32 MFMA.
// K_STEP=64, double-buffered LDS, ONE raw s_barrier per K-step, 2-deep
// register prefetch (counted vmcnt at ds_write). NT = K/64 even.
// ---------------------------------------------------------------------------
template<bool RELU, bool BIAS, bool EB, bool WBF16, bool LIN>
__device__ __forceinline__ void gemm_body(
    int tile, int nx,
    const unsigned short* __restrict__ A, int lda, int aoff1,
    const unsigned short* __restrict__ Bt0, const unsigned short* __restrict__ Bt1,
    int ldb, int Nh,
    const float* __restrict__ bias0, const float* __restrict__ bias1,
    const float* __restrict__ embc, const int* __restrict__ labels,
    const float* __restrict__ linW, float* __restrict__ hlin, float* __restrict__ tlin,
    int K, unsigned short* __restrict__ Cb, int ldc,
    unsigned short* As, unsigned short* Bs)
{
    const int tid = threadIdx.x;
    const int n0 = (tile % nx) * 64;
    const int m0 = (tile / nx) * 64;
    const int hf = (n0 >= Nh) ? 1 : 0;
    const unsigned short* Bt = hf ? Bt1 : Bt0;
    const int nc0 = n0 - (hf ? Nh : 0);
    const int aoff = hf ? aoff1 : 0;

    const int sr = tid >> 2;            // 0..63
    const int sk = (tid & 3) * 16;      // 0,16,32,48

    const unsigned short* Ap = A + (size_t)(m0 + sr) * lda + aoff + sk;
    const unsigned short* Bp = Bt + (size_t)(nc0 + sr) * ldb + sk;

    const int lane = tid & 63;
    const int wave = tid >> 6;
    const int wm = (wave & 1) * 32;
    const int wn = (wave >> 1) * 32;
    const int l15 = lane & 15;
    const int quad = lane >> 4;
    const int swo = sr * 72 + sk;
    const int aro = quad * 8;

    f32x4 acc00 = {}, acc01 = {}, acc10 = {}, acc11 = {};

    u16x8 pa0, pa1, pb0, pb1;           // even K-steps
    u16x8 qa0, qa1, qb0, qb1;           // odd K-steps

#define GLOADP(ko) { pa0 = *(const u16x8*)(Ap + (ko)); pa1 = *(const u16x8*)(Ap + (ko) + 8); \
                     pb0 = *(const u16x8*)(Bp + (ko)); pb1 = *(const u16x8*)(Bp + (ko) + 8); }
#define GLOADQ(ko) { qa0 = *(const u16x8*)(Ap + (ko)); qa1 = *(const u16x8*)(Ap + (ko) + 8); \
                     qb0 = *(const u16x8*)(Bp + (ko)); qb1 = *(const u16x8*)(Bp + (ko) + 8); }
#define SWRITEP(bi) { unsigned short* Aw = As + (bi) * BUFE; unsigned short* Bw = Bs + (bi) * BUFE; \
                      *(u16x8*)&Aw[swo] = pa0; *(u16x8*)&Aw[swo + 8] = pa1; \
                      *(u16x8*)&Bw[swo] = pb0; *(u16x8*)&Bw[swo + 8] = pb1; }
#define SWRITEQ(bi) { unsigned short* Aw = As + (bi) * BUFE; unsigned short* Bw = Bs + (bi) * BUFE; \
                      *(u16x8*)&Aw[swo] = qa0; *(u16x8*)&Aw[swo + 8] = qa1; \
                      *(u16x8*)&Bw[swo] = qb0; *(u16x8*)&Bw[swo + 8] = qb1; }
#define BAR() { asm volatile("s_waitcnt lgkmcnt(0)" ::: "memory"); \
                __builtin_amdgcn_s_barrier(); \
                __builtin_amdgcn_sched_barrier(0); }
#define MFMA8(bi) { const unsigned short* Ac = As + (bi) * BUFE; \
                    const unsigned short* Bc = Bs + (bi) * BUFE; \
        const bf16x8 fa0 = *(const bf16x8*)&Ac[(wm + l15) * 72 + aro]; \
        const bf16x8 fa1 = *(const bf16x8*)&Ac[(wm + 16 + l15) * 72 + aro]; \
        const bf16x8 fb0 = *(const bf16x8*)&Bc[(wn + l15) * 72 + aro]; \
        const bf16x8 fb1 = *(const bf16x8*)&Bc[(wn + 16 + l15) * 72 + aro]; \
        const bf16x8 ga0 = *(const bf16x8*)&Ac[(wm + l15) * 72 + aro + 32]; \
        const bf16x8 ga1 = *(const bf16x8*)&Ac[(wm + 16 + l15) * 72 + aro + 32]; \
        const bf16x8 gb0 = *(const bf16x8*)&Bc[(wn + l15) * 72 + aro + 32]; \
        const bf16x8 gb1 = *(const bf16x8*)&Bc[(wn + 16 + l15) * 72 + aro + 32]; \
        acc00 = __builtin_amdgcn_mfma_f32_16x16x32_bf16(fa0, fb0, acc00, 0, 0, 0); \
        acc01 = __builtin_amdgcn_mfma_f32_16x16x32_bf16(fa0, fb1, acc01, 0, 0, 0); \
        acc10 = __builtin_amdgcn_mfma_f32_16x16x32_bf16(fa1, fb0, acc10, 0, 0, 0); \
        acc11 = __builtin_amdgcn_mfma_f32_16x16x32_bf16(fa1, fb1, acc11, 0, 0, 0); \
        acc00 = __builtin_amdgcn_mfma_f32_16x16x32_bf16(ga0, gb0, acc00, 0, 0, 0); \
        acc01 = __builtin_amdgcn_mfma_f32_16x16x32_bf16(ga0, gb1, acc01, 0, 0, 0); \
        acc10 = __builtin_amdgcn_mfma_f32_16x16x32_bf16(ga1, gb0, acc10, 0, 0, 0); \
        acc11 = __builtin_amdgcn_mfma_f32_16x16x32_bf16(ga1, gb1, acc11, 0, 0, 0); }

    const int NT = K >> 6;              // even (6 or 12)

    GLOADP(0);
    GLOADQ(64);
    SWRITEP(0);

    for (int it = 0; it < NT; it += 2) {
        BAR();
        if (it + 2 < NT) GLOADP((it + 2) << 6);
        MFMA8(0);
        SWRITEQ(1);                      // counted vmcnt: waits K(it+1) only
        BAR();
        if (it + 3 < NT) GLOADQ((it + 3) << 6);
        MFMA8(1);
        if (it + 2 < NT) SWRITEP(0);     // counted vmcnt: waits K(it+2) only
    }

#undef GLOADP
#undef GLOADQ
#undef SWRITEP
#undef SWRITEQ
#undef BAR
#undef MFMA8

    // epilogue: C/D layout col=lane&15, row=quad*4+reg
    float bias_v0 = 0.f, bias_v1 = 0.f;
    if (BIAS) {
        const float* bb = hf ? bias1 : bias0;
        bias_v0 = bb[nc0 + wn + l15];
        bias_v1 = bb[nc0 + wn + 16 + l15];
    }
    const int col0 = n0 + wn + l15;
    const int col1 = col0 + 16;
    float2 lw0 = {0.f, 0.f}, lw1 = {0.f, 0.f};
    float* lout = nullptr;
    if (LIN) {
        lw0 = ((const float2*)linW)[col0];
        lw1 = ((const float2*)linW)[col1];
        lout = hf ? tlin : hlin;
    }
    const f32x4 accs[2][2] = {{acc00, acc01}, {acc10, acc11}};
    #pragma unroll
    for (int mi = 0; mi < 2; ++mi) {
        #pragma unroll
        for (int r = 0; r < 4; ++r) {
            const int row = m0 + wm + mi * 16 + quad * 4 + r;
            float v0 = accs[mi][0][r];
            float v1 = accs[mi][1][r];
            if (BIAS) { v0 += bias_v0; v1 += bias_v1; }
            if (EB) {
                const int lab = labels[row];
                v0 += embc[lab * 1536 + col0];
                v1 += embc[lab * 1536 + col1];
            }
            if (RELU) { v0 = fmaxf(v0, 0.f); v1 = fmaxf(v1, 0.f); }
            if (WBF16) {
                Cb[(size_t)row * ldc + col0] = f2bf(v0);
                Cb[(size_t)row * ldc + col1] = f2bf(v1);
            }
            if (LIN) {
                float s0 = v0 * lw0.x + v1 * lw1.x;
                float s1 = v0 * lw0.y + v1 * lw1.y;
                #pragma unroll
                for (int o = 8; o >= 1; o >>= 1) {
                    s0 += __shfl_xor(s0, o, 64);
                    s1 += __shfl_xor(s1, o, 64);
                }
                if (l15 == 0) {
                    atomicAdd(&lout[2 * row],     s0);
                    atomicAdd(&lout[2 * row + 1], s1);
                }
            }
        }
    }
}

// Generic GEMM kernel (stages 3-4), 2-D grid.
template<bool RELU, bool BIAS, bool EB, bool WBF16, bool LIN>
__global__ __launch_bounds__(256) void gemm_mfma(
    const unsigned short* __restrict__ A, int lda, int aoff1,
    const unsigned short* __restrict__ Bt0, const unsigned short* __restrict__ Bt1,
    int ldb, int Nh,
    const float* __restrict__ bias0, const float* __restrict__ bias1,
    const float* __restrict__ embc, const int* __restrict__ labels,
    const float* __restrict__ linW, float* __restrict__ hlin, float* __restrict__ tlin,
    int K, unsigned short* __restrict__ Cb, int ldc)
{
    __shared__ __align__(16) unsigned short As[2 * BUFE];
    __shared__ __align__(16) unsigned short Bs[2 * BUFE];
    gemm_body<RELU, BIAS, EB, WBF16, LIN>(
        blockIdx.y * gridDim.x + blockIdx.x, gridDim.x,
        A, lda, aoff1, Bt0, Bt1, ldb, Nh,
        bias0, bias1, embc, labels, linW, hlin, tlin,
        K, Cb, ldc, As, Bs);
}

// ---------------------------------------------------------------------------
// gemm1 + overlapped W2/bil transposes + relation binning.
//   blocks [0,384):     layer1 tiles
//   blocks [384,1248):  weight transposes (consumed by later launches)
//   blocks [1248,1312): bin 65536 relations into 256 tile-bins
//     bin = batch<<7 | (head>>6)<<4 | tail>>5 ; record packs
//     j:17 | label:1 | head&63:6 | tail&31:5 into one u32.
// ---------------------------------------------------------------------------
__global__ __launch_bounds__(256) void gemm1_plus(
    const unsigned short* __restrict__ Hbf,
    const unsigned short* __restrict__ W1ht, const unsigned short* __restrict__ W1tt,
    const float* __restrict__ embc, const int* __restrict__ ent_label,
    unsigned short* __restrict__ Y1bf,
    const float* __restrict__ hW2, const float* __restrict__ tW2,
    const float* __restrict__ bilW,
    unsigned short* __restrict__ W2ht, unsigned short* __restrict__ W2tt,
    unsigned short* __restrict__ bW0t, unsigned short* __restrict__ bW1t,
    const int* __restrict__ rel_head, const int* __restrict__ rel_tail,
    const int* __restrict__ rel_label,
    int* __restrict__ counts, unsigned* __restrict__ bins)
{
    __shared__ __align__(16) unsigned short As[2 * BUFE];
    __shared__ __align__(16) unsigned short Bs[2 * BUFE];
    const int bid = blockIdx.x;
    if (bid >= 1248) {
        // ---- relation binning (64 blocks x 1024 relations)
        const int base = (bid - 1248) * 1024;
        #pragma unroll
        for (int k = 0; k < 4; ++k) {
            const int j = base + k * 256 + threadIdx.x;
            const int h = rel_head[j];
            const int t = rel_tail[j];
            const int lab = rel_label[j];
            const int bin = ((j >> 15) << 7) | ((h >> 6) << 4) | (t >> 5);
            const int slot = atomicAdd(&counts[bin], 1);
            bins[(bin << 10) | slot] =
                (unsigned)j | ((unsigned)lab << 17) |
                ((unsigned)(h & 63) << 18) | ((unsigned)(t & 31) << 24);
        }
        return;
    }
    if (bid >= 384) {
        const int task = bid - 384;
        if (task < 288)      wtrans(hW2, W2ht, 768, 384, task, As);
        else if (task < 576) wtrans(tW2, W2tt, 768, 384, task - 288, As);
        else if (task < 720) wtrans(bilW, bW0t, 384, 384, task - 576, As);
        else                 wtrans(bilW + 384 * 384, bW1t, 384, 384, task - 720, As);
        return;
    }
    gemm_body<true, false, true, true, false>(
        bid, 24, Hbf, 768, 0, W1ht, W1tt, 768, 768,
        nullptr, nullptr, embc, ent_label, nullptr, nullptr, nullptr,
        768, Y1bf, 1536, As, Bs);
}

// ---------------------------------------------------------------------------
// Fused score+gather+CE: one block per (m-block 64, t-block 32) tile.
// Phase-split K-loop: steps 0-5 accumulate o=0 (hW cols 0..383), steps 6-11
// accumulate o=1 (hW cols 384..767); identical B (tails) both phases.
// Scores parked in LDS; block processes ONLY its bin's relations (~256).
// ---------------------------------------------------------------------------
__global__ __launch_bounds__(256) void score_rel(
    const unsigned short* __restrict__ hWbf, const unsigned short* __restrict__ HTbf,
    const float* __restrict__ hlin, const float* __restrict__ tlin,
    const float* __restrict__ lin_b,
    const int* __restrict__ counts, const unsigned* __restrict__ bins,
    float* __restrict__ out)
{
    __shared__ __align__(16) unsigned short As[2][64 * 72];   // 18432 B
    __shared__ __align__(16) unsigned short Bs[2][32 * 72];   //  9216 B
    __shared__ float wsum[4];

    const int tid = threadIdx.x;
    const int t0 = blockIdx.x * 32;      // tail-col block (0..480)
    const int m0 = blockIdx.y * 64;      // mh row block (0..960)
    const int batch = m0 >> 9;

    // A staging: 64 rows x 64 k per step (2 x u16x8 per thread)
    const int asr = tid >> 2;            // 0..63
    const int ask = (tid & 3) * 16;      // 0,16,32,48
    const unsigned short* Ap = hWbf + (size_t)(m0 + asr) * 768 + ask;
    // B staging: 32 rows x 64 k per step (1 x u16x8 per thread)
    const int bsr = tid >> 3;            // 0..31
    const int bsk = (tid & 7) * 8;       // 0..56
    const unsigned short* Bp = HTbf + (size_t)(batch * 512 + t0 + bsr) * 768 + 384 + bsk;

    const int lane = tid & 63;
    const int wave = tid >> 6;
    const int wm = (wave & 1) * 32;      // 2 m-waves
    const int wn = (wave >> 1) * 16;     // 2 n-waves x 16 cols
    const int l15 = lane & 15;
    const int quad = lane >> 4;
    const int aro = quad * 8;

    f32x4 p00 = {}, p01 = {};            // o=0: m-frag 0/1
    f32x4 p10 = {}, p11 = {};            // o=1

    for (int it = 0; it < 12; ++it) {
        const int koA = (it < 6) ? it * 64 : (it - 6) * 64 + 384;
        const int koB = ((it < 6) ? it : it - 6) * 64;
        const u16x8 av0 = *(const u16x8*)(Ap + koA);
        const u16x8 av1 = *(const u16x8*)(Ap + koA + 8);
        const u16x8 bv  = *(const u16x8*)(Bp + koB);
        __syncthreads();
        *(u16x8*)&As[it & 1][asr * 72 + ask]     = av0;
        *(u16x8*)&As[it & 1][asr * 72 + ask + 8] = av1;
        *(u16x8*)&Bs[it & 1][bsr * 72 + bsk]     = bv;
        __syncthreads();
        const unsigned short* Ac = As[it & 1];
        const unsigned short* Bc = Bs[it & 1];
        const bf16x8 fa0 = *(const bf16x8*)&Ac[(wm + l15) * 72 + aro];
        const bf16x8 fa1 = *(const bf16x8*)&Ac[(wm + 16 + l15) * 72 + aro];
        const bf16x8 fb  = *(const bf16x8*)&Bc[(wn + l15) * 72 + aro];
        const bf16x8 ga0 = *(const bf16x8*)&Ac[(wm + l15) * 72 + aro + 32];
        const bf16x8 ga1 = *(const bf16x8*)&Ac[(wm + 16 + l15) * 72 + aro + 32];
        const bf16x8 gb  = *(const bf16x8*)&Bc[(wn + l15) * 72 + aro + 32];
        if (it < 6) {
            p00 = __builtin_amdgcn_mfma_f32_16x16x32_bf16(fa0, fb, p00, 0, 0, 0);
            p01 = __builtin_amdgcn_mfma_f32_16x16x32_bf16(fa1, fb, p01, 0, 0, 0);
            p00 = __builtin_amdgcn_mfma_f32_16x16x32_bf16(ga0, gb, p00, 0, 0, 0);
            p01 = __builtin_amdgcn_mfma_f32_16x16x32_bf16(ga1, gb, p01, 0, 0, 0);
        } else {
            p10 = __builtin_amdgcn_mfma_f32_16x16x32_bf16(fa0, fb, p10, 0, 0, 0);
            p11 = __builtin_amdgcn_mfma_f32_16x16x32_bf16(fa1, fb, p11, 0, 0, 0);
            p10 = __builtin_amdgcn_mfma_f32_16x16x32_bf16(ga0, gb, p10, 0, 0, 0);
            p11 = __builtin_amdgcn_mfma_f32_16x16x32_bf16(ga1, gb, p11, 0, 0, 0);
        }
    }

    // park scores in LDS (alias over As): 2 planes of [64][33] fp32 = 16896 B
    __syncthreads();                     // all waves done reading As/Bs
    float* Sl = (float*)&As[0][0];
    const int col = wn + l15;            // 0..31
    #pragma unroll
    for (int mi = 0; mi < 2; ++mi) {
        #pragma unroll
        for (int r = 0; r < 4; ++r) {
            const int row = wm + mi * 16 + quad * 4 + r;
            Sl[row * 33 + col]           = mi ? p01[r] : p00[r];
            Sl[64 * 33 + row * 33 + col] = mi ? p11[r] : p10[r];
        }
    }
    __syncthreads();

    // process this tile's bin (~256 relations, 1/thread)
    const int bin = (batch << 7) | (((m0 >> 6) & 7) << 4) | (t0 >> 5);
    const int cnt = counts[bin];
    const unsigned* mybins = bins + (bin << 10);
    const float lb0 = lin_b[0], lb1 = lin_b[1];
    float ce = 0.f;
    for (int i = tid; i < cnt; i += 256) {
        const unsigned rec = mybins[i];
        const int j   = rec & 0x1FFFF;
        const int lab = (rec >> 17) & 1;
        const int h6  = (rec >> 18) & 63;
        const int t5  = (rec >> 24) & 31;
        const int mh = m0 + h6;
        const int mt = batch * 512 + t0 + t5;
        const float2 hl = ((const float2*)hlin)[mh];
        const float2 tl = ((const float2*)tlin)[mt];
        const int so = h6 * 33 + t5;
        const float z0 = Sl[so]           + hl.x + tl.x + lb0;
        const float z1 = Sl[64 * 33 + so] + hl.y + tl.y + lb1;
        out[1 + 2 * (size_t)j] = z0;
        out[2 + 2 * (size_t)j] = z1;
        const float mx = fmaxf(z0, z1);
        const float mn = fminf(z0, z1);
        ce += mx + log1pf(expf(mn - mx)) - (lab ? z1 : z0);
    }
    #pragma unroll
    for (int o = 32; o >= 1; o >>= 1) ce += __shfl_xor(ce, o, 64);
    if (lane == 0) wsum[wave] = ce;
    __syncthreads();
    if (tid == 0)
        atomicAdd(out, (wsum[0] + wsum[1] + wsum[2] + wsum[3]) * (1.0f / (float)RR));
}

// ---------------------------------------------------------------------------
extern "C" void kernel_launch(void* const* d_in, const int* in_sizes, int n_in,
                              void* d_out, int out_size, void* d_ws, size_t ws_size,
                              hipStream_t stream) {
    const float* hidden    = (const float*)d_in[0];
    const int*   ent_start = (const int*)d_in[1];
    const int*   ent_label = (const int*)d_in[2];
    const int*   rel_head  = (const int*)d_in[3];
    const int*   rel_tail  = (const int*)d_in[4];
    const int*   rel_label = (const int*)d_in[5];
    const float* emb       = (const float*)d_in[6];
    const float* head_W1   = (const float*)d_in[7];
    const float* head_b1   = (const float*)d_in[8];
    const float* head_W2   = (const float*)d_in[9];
    const float* head_b2   = (const float*)d_in[10];
    const float* tail_W1   = (const float*)d_in[11];
    const float* tail_b1   = (const float*)d_in[12];
    const float* tail_W2   = (const float*)d_in[13];
    const float* tail_b2   = (const float*)d_in[14];
    const float* bil_W     = (const float*)d_in[15];
    const float* lin_W     = (const float*)d_in[16];
    const float* lin_b     = (const float*)d_in[17];
    float* out = (float*)d_out;

    // Workspace carve-up (256B-aligned chunks)
    char* w = (char*)d_ws;
    auto carve = [&](size_t bytes) {
        char* p = w; w += (bytes + 255) & ~(size_t)255; return p;
    };
    unsigned short* Hbf  = (unsigned short*)carve((size_t)MM * 768 * 2);
    unsigned short* Y1bf = (unsigned short*)carve((size_t)MM * 1536 * 2);
    unsigned short* HTbf = (unsigned short*)carve((size_t)MM * 768 * 2);
    unsigned short* hWbf = (unsigned short*)carve((size_t)MM * 768 * 2);
    unsigned short* W1ht = (unsigned short*)carve((size_t)768 * 768 * 2);
    unsigned short* W1tt = (unsigned short*)carve((size_t)768 * 768 * 2);
    unsigned short* W2ht = (unsigned short*)carve((size_t)384 * 768 * 2);
    unsigned short* W2tt = (unsigned short*)carve((size_t)384 * 768 * 2);
    unsigned short* bW0t = (unsigned short*)carve((size_t)384 * 384 * 2);
    unsigned short* bW1t = (unsigned short*)carve((size_t)384 * 384 * 2);
    float*          embc = (float*)carve((size_t)3 * 1536 * 4);
    float*          hlin = (float*)carve(2048 * 4);
    float*          tlin = (float*)carve(2048 * 4);
    int*            counts = (int*)carve(256 * 4);
    unsigned*       bins = (unsigned*)carve((size_t)256 * 1024 * 4);

    // 1) W1 transpose + hidden gather + embc fold + zeroing (incl. counts)
    prep<<<2201, 256, 0, stream>>>(
        head_W1, tail_W1, W1ht, W1tt,
        hidden, ent_start, emb, head_b1, tail_b1, Hbf, embc,
        hlin, tlin, counts, out);

    // 2) layer1 (384 tiles) + W2/bil transposes (864) + rel binning (64)
    gemm1_plus<<<1312, 256, 0, stream>>>(
        Hbf, W1ht, W1tt, embc, ent_label, Y1bf,
        head_W2, tail_W2, bil_W, W2ht, W2tt, bW0t, bW1t,
        rel_head, rel_tail, rel_label, counts, bins);

    // 3) layer2: HTbf = relu(Y1 @ [W2h|W2t] + b2), N=768 (Nh=384), K=768,
    //    tail half reads Y1 cols 768..; epilogue fuses lin_proj via atomics
    gemm_mfma<true, true, false, true, true>
        <<<dim3(12, 16), 256, 0, stream>>>(
        Y1bf, 1536, 768, W2ht, W2tt, 768, 384, head_b2, tail_b2,
        nullptr, nullptr, lin_W, hlin, tlin, 768, HTbf, 768);

    // 4) bilinear left product: hWbf = heads @ bil_W[o], N=768 (Nh=384), K=384
    gemm_mfma<false, false, false, true, false>
        <<<dim3(12, 16), 256, 0, stream>>>(
        HTbf, 768, 0, bW0t, bW1t, 384, 384, nullptr, nullptr,
        nullptr, nullptr, nullptr, nullptr, nullptr, 384, hWbf, 768);

    // 5) fused score + binned relation gather + CE
    score_rel<<<dim3(16, 16), 256, 0, stream>>>(
        hWbf, HTbf, hlin, tlin, lin_b,
        counts, bins, out);
}

// Round 9
// 143.790 us; speedup vs baseline: 1.6394x; 1.1364x over previous
//
#include <hip/hip_runtime.h>
#include <math.h>

// Problem constants
#define BB 2
#define LL 512
#define HH 768
#define EE 512
#define RR 32768
#define H2 384
#define MM 1024   // B*E entity rows

typedef __attribute__((ext_vector_type(8))) short     bf16x8;  // MFMA A/B frag
typedef __attribute__((ext_vector_type(4))) float     f32x4;   // MFMA C/D frag
typedef __attribute__((ext_vector_type(8))) unsigned short u16x8;

#define BUFE (64 * 72)    // one LDS buffer: 64 rows x (64+8) bf16

__device__ __forceinline__ unsigned short f2bf(float f) {
    unsigned int u = __float_as_uint(f);
    u = (u + 0x7FFFu + ((u >> 16) & 1u)) >> 16;   // round-to-nearest-even
    return (unsigned short)u;
}

// ---------------------------------------------------------------------------
// 32x32 weight transpose tile: [K][N] fp32 -> [N][K] bf16. T = 32*40 ushorts.
// ---------------------------------------------------------------------------
__device__ __forceinline__ void wtrans(const float* __restrict__ src,
                                       unsigned short* __restrict__ dst,
                                       int K, int N, int tile, unsigned short* T)
{
    const int t = threadIdx.x;
    const int tn = N >> 5;
    const int n0 = (tile % tn) * 32;
    const int k0 = (tile / tn) * 32;
    const int r  = t >> 3;           // 0..31 (k within tile)
    const int c4 = (t & 7) * 4;      // 0..28 (n within tile)
    const float4 g = *(const float4*)(src + (size_t)(k0 + r) * N + n0 + c4);
    T[(c4 + 0) * 40 + r] = f2bf(g.x);
    T[(c4 + 1) * 40 + r] = f2bf(g.y);
    T[(c4 + 2) * 40 + r] = f2bf(g.z);
    T[(c4 + 3) * 40 + r] = f2bf(g.w);
    __syncthreads();
    const int n  = t >> 3;           // 0..31
    const int k4 = (t & 7) * 4;      // 0..28
    *(ushort4*)(dst + (size_t)(n0 + n) * K + k0 + k4) = *(ushort4*)&T[n * 40 + k4];
}

// ---------------------------------------------------------------------------
// prep:
//   [0,576)     W1 head top-half transpose -> W1ht
//   [576,1152)  W1 tail top-half transpose -> W1tt
//   [1152,2176) gather hidden[b, ent_start] -> Hbf bf16 [1024][768]
//   [2176,2200) embc[l][n] = b1[n] + sum_k emb[l][k]*W1[768+k][n]
//   2200        zero hlin/tlin accumulators + out[0]
// ---------------------------------------------------------------------------
__global__ __launch_bounds__(256) void prep(
    const float* __restrict__ hW1, const float* __restrict__ tW1,
    unsigned short* __restrict__ W1ht, unsigned short* __restrict__ W1tt,
    const float* __restrict__ hidden, const int* __restrict__ ent_start,
    const float* __restrict__ emb,
    const float* __restrict__ hb1, const float* __restrict__ tb1,
    unsigned short* __restrict__ Hbf, float* __restrict__ embc,
    float* __restrict__ hlin, float* __restrict__ tlin, float* __restrict__ out)
{
    __shared__ unsigned short T[32 * 40];
    __shared__ float red[4][192];
    const int bid = blockIdx.x;
    const int t = threadIdx.x;

    if (bid == 2200) {
        const float4 z = {0.f, 0.f, 0.f, 0.f};
        ((float4*)hlin)[t] = z; ((float4*)hlin)[256 + t] = z;
        ((float4*)tlin)[t] = z; ((float4*)tlin)[256 + t] = z;
        if (t == 0) out[0] = 0.f;
        return;
    }

    if (bid >= 2176) {
        // ---- embc: per-(label, col) folded bias table
        const int eb = bid - 2176;           // 0..23
        const int tc = t & 63;
        const int kg = t >> 6;               // 0..3 k-group
        const int n = eb * 64 + tc;          // global col 0..1535
        const float* W = (n < 768) ? hW1 : tW1;
        const int cc = (n < 768) ? n : n - 768;
        float a0 = 0.f, a1 = 0.f, a2 = 0.f;
        const int kbeg = kg * 192;
        #pragma unroll 8
        for (int k = kbeg; k < kbeg + 192; ++k) {
            const float w = W[(size_t)(768 + k) * 768 + cc];
            a0 += emb[k] * w;
            a1 += emb[768 + k] * w;
            a2 += emb[1536 + k] * w;
        }
        red[kg][0 * 64 + tc] = a0;
        red[kg][1 * 64 + tc] = a1;
        red[kg][2 * 64 + tc] = a2;
        __syncthreads();
        if (kg == 0) {
            const float b = (n < 768) ? hb1[n] : tb1[n - 768];
            #pragma unroll
            for (int l = 0; l < 3; ++l) {
                embc[l * 1536 + n] = b + red[0][l * 64 + tc] + red[1][l * 64 + tc]
                                       + red[2][l * 64 + tc] + red[3][l * 64 + tc];
            }
        }
        return;
    }

    if (bid >= 1152) {
        // ---- gather hidden[b, ent_start[m]] as bf16 (768 cols)
        const int m = bid - 1152;            // 0..1023
        if (t >= 96) return;
        const int b = m >> 9;
        const int idx = ent_start[m];
        const float4* s = (const float4*)(hidden + (size_t)(b * LL + idx) * HH);
        const float4 v0 = s[2 * t];
        const float4 v1 = s[2 * t + 1];
        u16x8 o;
        o[0] = f2bf(v0.x); o[1] = f2bf(v0.y); o[2] = f2bf(v0.z); o[3] = f2bf(v0.w);
        o[4] = f2bf(v1.x); o[5] = f2bf(v1.y); o[6] = f2bf(v1.z); o[7] = f2bf(v1.w);
        *(u16x8*)(Hbf + (size_t)m * 768 + 8 * t) = o;
        return;
    }

    // ---- W1 transposes (top halves only; bottom folded into embc)
    if (bid < 576) wtrans(hW1, W1ht, 768, 768, bid, T);
    else           wtrans(tW1, W1tt, 768, 768, bid - 576, T);
}

// ---------------------------------------------------------------------------
// bf16 MFMA GEMM body. 64x64 tile, 256 threads (4 waves, 2x2), 16x16x32 MFMA.
// K_STEP=64, double-buffered LDS, ONE raw s_barrier per K-step, 2-deep
// register prefetch (counted vmcnt at ds_write). NT = K/64 even.
// ---------------------------------------------------------------------------
template<bool RELU, bool BIAS, bool EB, bool WBF16, bool LIN>
__device__ __forceinline__ void gemm_body(
    int tile, int nx,
    const unsigned short* __restrict__ A, int lda, int aoff1,
    const unsigned short* __restrict__ Bt0, const unsigned short* __restrict__ Bt1,
    int ldb, int Nh,
    const float* __restrict__ bias0, const float* __restrict__ bias1,
    const float* __restrict__ embc, const int* __restrict__ labels,
    const float* __restrict__ linW, float* __restrict__ hlin, float* __restrict__ tlin,
    int K, unsigned short* __restrict__ Cb, int ldc,
    unsigned short* As, unsigned short* Bs)
{
    const int tid = threadIdx.x;
    const int n0 = (tile % nx) * 64;
    const int m0 = (tile / nx) * 64;
    const int hf = (n0 >= Nh) ? 1 : 0;
    const unsigned short* Bt = hf ? Bt1 : Bt0;
    const int nc0 = n0 - (hf ? Nh : 0);
    const int aoff = hf ? aoff1 : 0;

    const int sr = tid >> 2;            // 0..63
    const int sk = (tid & 3) * 16;      // 0,16,32,48

    const unsigned short* Ap = A + (size_t)(m0 + sr) * lda + aoff + sk;
    const unsigned short* Bp = Bt + (size_t)(nc0 + sr) * ldb + sk;

    const int lane = tid & 63;
    const int wave = tid >> 6;
    const int wm = (wave & 1) * 32;
    const int wn = (wave >> 1) * 32;
    const int l15 = lane & 15;
    const int quad = lane >> 4;
    const int swo = sr * 72 + sk;
    const int aro = quad * 8;

    f32x4 acc00 = {}, acc01 = {}, acc10 = {}, acc11 = {};

    u16x8 pa0, pa1, pb0, pb1;           // even K-steps
    u16x8 qa0, qa1, qb0, qb1;           // odd K-steps

#define GLOADP(ko) { pa0 = *(const u16x8*)(Ap + (ko)); pa1 = *(const u16x8*)(Ap + (ko) + 8); \
                     pb0 = *(const u16x8*)(Bp + (ko)); pb1 = *(const u16x8*)(Bp + (ko) + 8); }
#define GLOADQ(ko) { qa0 = *(const u16x8*)(Ap + (ko)); qa1 = *(const u16x8*)(Ap + (ko) + 8); \
                     qb0 = *(const u16x8*)(Bp + (ko)); qb1 = *(const u16x8*)(Bp + (ko) + 8); }
#define SWRITEP(bi) { unsigned short* Aw = As + (bi) * BUFE; unsigned short* Bw = Bs + (bi) * BUFE; \
                      *(u16x8*)&Aw[swo] = pa0; *(u16x8*)&Aw[swo + 8] = pa1; \
                      *(u16x8*)&Bw[swo] = pb0; *(u16x8*)&Bw[swo + 8] = pb1; }
#define SWRITEQ(bi) { unsigned short* Aw = As + (bi) * BUFE; unsigned short* Bw = Bs + (bi) * BUFE; \
                      *(u16x8*)&Aw[swo] = qa0; *(u16x8*)&Aw[swo + 8] = qa1; \
                      *(u16x8*)&Bw[swo] = qb0; *(u16x8*)&Bw[swo + 8] = qb1; }
#define BAR() { asm volatile("s_waitcnt lgkmcnt(0)" ::: "memory"); \
                __builtin_amdgcn_s_barrier(); \
                __builtin_amdgcn_sched_barrier(0); }
#define MFMA8(bi) { const unsigned short* Ac = As + (bi) * BUFE; \
                    const unsigned short* Bc = Bs + (bi) * BUFE; \
        const bf16x8 fa0 = *(const bf16x8*)&Ac[(wm + l15) * 72 + aro]; \
        const bf16x8 fa1 = *(const bf16x8*)&Ac[(wm + 16 + l15) * 72 + aro]; \
        const bf16x8 fb0 = *(const bf16x8*)&Bc[(wn + l15) * 72 + aro]; \
        const bf16x8 fb1 = *(const bf16x8*)&Bc[(wn + 16 + l15) * 72 + aro]; \
        const bf16x8 ga0 = *(const bf16x8*)&Ac[(wm + l15) * 72 + aro + 32]; \
        const bf16x8 ga1 = *(const bf16x8*)&Ac[(wm + 16 + l15) * 72 + aro + 32]; \
        const bf16x8 gb0 = *(const bf16x8*)&Bc[(wn + l15) * 72 + aro + 32]; \
        const bf16x8 gb1 = *(const bf16x8*)&Bc[(wn + 16 + l15) * 72 + aro + 32]; \
        acc00 = __builtin_amdgcn_mfma_f32_16x16x32_bf16(fa0, fb0, acc00, 0, 0, 0); \
        acc01 = __builtin_amdgcn_mfma_f32_16x16x32_bf16(fa0, fb1, acc01, 0, 0, 0); \
        acc10 = __builtin_amdgcn_mfma_f32_16x16x32_bf16(fa1, fb0, acc10, 0, 0, 0); \
        acc11 = __builtin_amdgcn_mfma_f32_16x16x32_bf16(fa1, fb1, acc11, 0, 0, 0); \
        acc00 = __builtin_amdgcn_mfma_f32_16x16x32_bf16(ga0, gb0, acc00, 0, 0, 0); \
        acc01 = __builtin_amdgcn_mfma_f32_16x16x32_bf16(ga0, gb1, acc01, 0, 0, 0); \
        acc10 = __builtin_amdgcn_mfma_f32_16x16x32_bf16(ga1, gb0, acc10, 0, 0, 0); \
        acc11 = __builtin_amdgcn_mfma_f32_16x16x32_bf16(ga1, gb1, acc11, 0, 0, 0); }

    const int NT = K >> 6;              // even (6 or 12)

    GLOADP(0);
    GLOADQ(64);
    SWRITEP(0);

    for (int it = 0; it < NT; it += 2) {
        BAR();
        if (it + 2 < NT) GLOADP((it + 2) << 6);
        MFMA8(0);
        SWRITEQ(1);                      // counted vmcnt: waits K(it+1) only
        BAR();
        if (it + 3 < NT) GLOADQ((it + 3) << 6);
        MFMA8(1);
        if (it + 2 < NT) SWRITEP(0);     // counted vmcnt: waits K(it+2) only
    }

#undef GLOADP
#undef GLOADQ
#undef SWRITEP
#undef SWRITEQ
#undef BAR
#undef MFMA8

    // epilogue: C/D layout col=lane&15, row=quad*4+reg
    float bias_v0 = 0.f, bias_v1 = 0.f;
    if (BIAS) {
        const float* bb = hf ? bias1 : bias0;
        bias_v0 = bb[nc0 + wn + l15];
        bias_v1 = bb[nc0 + wn + 16 + l15];
    }
    const int col0 = n0 + wn + l15;
    const int col1 = col0 + 16;
    float2 lw0 = {0.f, 0.f}, lw1 = {0.f, 0.f};
    float* lout = nullptr;
    if (LIN) {
        lw0 = ((const float2*)linW)[col0];
        lw1 = ((const float2*)linW)[col1];
        lout = hf ? tlin : hlin;
    }
    const f32x4 accs[2][2] = {{acc00, acc01}, {acc10, acc11}};
    #pragma unroll
    for (int mi = 0; mi < 2; ++mi) {
        #pragma unroll
        for (int r = 0; r < 4; ++r) {
            const int row = m0 + wm + mi * 16 + quad * 4 + r;
            float v0 = accs[mi][0][r];
            float v1 = accs[mi][1][r];
            if (BIAS) { v0 += bias_v0; v1 += bias_v1; }
            if (EB) {
                const int lab = labels[row];
                v0 += embc[lab * 1536 + col0];
                v1 += embc[lab * 1536 + col1];
            }
            if (RELU) { v0 = fmaxf(v0, 0.f); v1 = fmaxf(v1, 0.f); }
            if (WBF16) {
                Cb[(size_t)row * ldc + col0] = f2bf(v0);
                Cb[(size_t)row * ldc + col1] = f2bf(v1);
            }
            if (LIN) {
                float s0 = v0 * lw0.x + v1 * lw1.x;
                float s1 = v0 * lw0.y + v1 * lw1.y;
                #pragma unroll
                for (int o = 8; o >= 1; o >>= 1) {
                    s0 += __shfl_xor(s0, o, 64);
                    s1 += __shfl_xor(s1, o, 64);
                }
                if (l15 == 0) {
                    atomicAdd(&lout[2 * row],     s0);
                    atomicAdd(&lout[2 * row + 1], s1);
                }
            }
        }
    }
}

// Generic GEMM kernel (stages 3-4), 2-D grid.
template<bool RELU, bool BIAS, bool EB, bool WBF16, bool LIN>
__global__ __launch_bounds__(256) void gemm_mfma(
    const unsigned short* __restrict__ A, int lda, int aoff1,
    const unsigned short* __restrict__ Bt0, const unsigned short* __restrict__ Bt1,
    int ldb, int Nh,
    const float* __restrict__ bias0, const float* __restrict__ bias1,
    const float* __restrict__ embc, const int* __restrict__ labels,
    const float* __restrict__ linW, float* __restrict__ hlin, float* __restrict__ tlin,
    int K, unsigned short* __restrict__ Cb, int ldc)
{
    __shared__ __align__(16) unsigned short As[2 * BUFE];
    __shared__ __align__(16) unsigned short Bs[2 * BUFE];
    gemm_body<RELU, BIAS, EB, WBF16, LIN>(
        blockIdx.y * gridDim.x + blockIdx.x, gridDim.x,
        A, lda, aoff1, Bt0, Bt1, ldb, Nh,
        bias0, bias1, embc, labels, linW, hlin, tlin,
        K, Cb, ldc, As, Bs);
}

// ---------------------------------------------------------------------------
// gemm1 + overlapped W2/bil transposes + contention-free relation binning.
//   blocks [0,384):     layer1 tiles
//   blocks [384,1248):  weight transposes (consumed by later launches)
//   blocks [1248,1312): bin 1024 relations each via LDS histogram.
//     bin = batch<<7 | (head>>6)<<4 | tail>>5.  Each block blkb (0..31 within
//     its batch) owns segment bins[bin*1024 + blkb*32 .. +32) and writes its
//     count to counts2[bin*32 + blkb] NON-atomically (single writer).
//     Record: j:17 | label:1 | head&63:6 | tail&31:5.
// ---------------------------------------------------------------------------
__global__ __launch_bounds__(256) void gemm1_plus(
    const unsigned short* __restrict__ Hbf,
    const unsigned short* __restrict__ W1ht, const unsigned short* __restrict__ W1tt,
    const float* __restrict__ embc, const int* __restrict__ ent_label,
    unsigned short* __restrict__ Y1bf,
    const float* __restrict__ hW2, const float* __restrict__ tW2,
    const float* __restrict__ bilW,
    unsigned short* __restrict__ W2ht, unsigned short* __restrict__ W2tt,
    unsigned short* __restrict__ bW0t, unsigned short* __restrict__ bW1t,
    const int* __restrict__ rel_head, const int* __restrict__ rel_tail,
    const int* __restrict__ rel_label,
    int* __restrict__ counts2, unsigned* __restrict__ bins)
{
    __shared__ __align__(16) unsigned short As[2 * BUFE];
    __shared__ __align__(16) unsigned short Bs[2 * BUFE];
    const int bid = blockIdx.x;
    if (bid >= 1248) {
        // ---- relation binning, LDS-local (no global atomics)
        __shared__ int lcnt[128];
        const int tid = threadIdx.x;
        const int blk = bid - 1248;          // 0..63
        const int batch = blk >> 5;
        const int blkb = blk & 31;           // block index within batch
        if (tid < 128) lcnt[tid] = 0;
        __syncthreads();
        const int base = blk * 1024;
        #pragma unroll
        for (int k = 0; k < 4; ++k) {
            const int j = base + k * 256 + tid;
            const int h = rel_head[j];
            const int t = rel_tail[j];
            const int lab = rel_label[j];
            const int lbin = ((h >> 6) << 4) | (t >> 5);          // 0..127
            const int slot = atomicAdd(&lcnt[lbin], 1);           // LDS atomic
            const int gbin = (batch << 7) | lbin;
            bins[(gbin << 10) | (blkb << 5) | slot] =
                (unsigned)j | ((unsigned)lab << 17) |
                ((unsigned)(h & 63) << 18) | ((unsigned)(t & 31) << 24);
        }
        __syncthreads();
        if (tid < 128)
            counts2[(((batch << 7) | tid) << 5) | blkb] = lcnt[tid];
        return;
    }
    if (bid >= 384) {
        const int task = bid - 384;
        if (task < 288)      wtrans(hW2, W2ht, 768, 384, task, As);
        else if (task < 576) wtrans(tW2, W2tt, 768, 384, task - 288, As);
        else if (task < 720) wtrans(bilW, bW0t, 384, 384, task - 576, As);
        else                 wtrans(bilW + 384 * 384, bW1t, 384, 384, task - 720, As);
        return;
    }
    gemm_body<true, false, true, true, false>(
        bid, 24, Hbf, 768, 0, W1ht, W1tt, 768, 768,
        nullptr, nullptr, embc, ent_label, nullptr, nullptr, nullptr,
        768, Y1bf, 1536, As, Bs);
}

// ---------------------------------------------------------------------------
// Fused score+gather+CE: one block per (m-block 64, t-block 32) tile.
// Phase-split K-loop (12 steps, fully unrolled, 2-deep prefetch, raw
// barriers): steps 0-5 accumulate o=0 (hW cols 0..383), 6-11 o=1 (cols
// 384..767); identical B (tails) both phases. Scores parked in LDS; block
// processes only its bin's relations via the 32-segment list.
// ---------------------------------------------------------------------------
__global__ __launch_bounds__(256) void score_rel(
    const unsigned short* __restrict__ hWbf, const unsigned short* __restrict__ HTbf,
    const float* __restrict__ hlin, const float* __restrict__ tlin,
    const float* __restrict__ lin_b,
    const int* __restrict__ counts2, const unsigned* __restrict__ bins,
    float* __restrict__ out)
{
    __shared__ __align__(16) unsigned short As[2][64 * 72];   // 18432 B
    __shared__ __align__(16) unsigned short Bs[2][32 * 72];   //  9216 B
    __shared__ float wsum[4];
    __shared__ int cbuf[32];

    const int tid = threadIdx.x;
    const int t0 = blockIdx.x * 32;      // tail-col block (0..480)
    const int m0 = blockIdx.y * 64;      // mh row block (0..960)
    const int batch = m0 >> 9;

    // A staging: 64 rows x 64 k per step (2 x u16x8 per thread)
    const int asr = tid >> 2;            // 0..63
    const int ask = (tid & 3) * 16;      // 0,16,32,48
    const unsigned short* Ap = hWbf + (size_t)(m0 + asr) * 768 + ask;
    // B staging: 32 rows x 64 k per step (1 x u16x8 per thread)
    const int bsr = tid >> 3;            // 0..31
    const int bsk = (tid & 7) * 8;       // 0..56
    const unsigned short* Bp = HTbf + (size_t)(batch * 512 + t0 + bsr) * 768 + 384 + bsk;

    const int lane = tid & 63;
    const int wave = tid >> 6;
    const int wm = (wave & 1) * 32;      // 2 m-waves
    const int wn = (wave >> 1) * 16;     // 2 n-waves x 16 cols
    const int l15 = lane & 15;
    const int quad = lane >> 4;
    const int aro = quad * 8;
    const int aswo = asr * 72 + ask;
    const int bswo = bsr * 72 + bsk;

    f32x4 p00 = {}, p01 = {};            // o=0: m-frag 0/1
    f32x4 p10 = {}, p11 = {};            // o=1

    // k offsets per step (compile-time under full unroll)
#define KOA(it) (((it) < 6) ? (it) * 64 : ((it) - 6) * 64 + 384)
#define KOB(it) ((((it) < 6) ? (it) : (it) - 6) * 64)

    u16x8 pa0, pa1, pbv;                 // even steps
    u16x8 qa0, qa1, qbv;                 // odd steps

#define SGLOADP(it) { pa0 = *(const u16x8*)(Ap + KOA(it)); pa1 = *(const u16x8*)(Ap + KOA(it) + 8); \
                      pbv = *(const u16x8*)(Bp + KOB(it)); }
#define SGLOADQ(it) { qa0 = *(const u16x8*)(Ap + KOA(it)); qa1 = *(const u16x8*)(Ap + KOA(it) + 8); \
                      qbv = *(const u16x8*)(Bp + KOB(it)); }
#define SSWRITEP(bi) { *(u16x8*)&As[bi][aswo] = pa0; *(u16x8*)&As[bi][aswo + 8] = pa1; \
                       *(u16x8*)&Bs[bi][bswo] = pbv; }
#define SSWRITEQ(bi) { *(u16x8*)&As[bi][aswo] = qa0; *(u16x8*)&As[bi][aswo + 8] = qa1; \
                       *(u16x8*)&Bs[bi][bswo] = qbv; }
#define SBAR() { asm volatile("s_waitcnt lgkmcnt(0)" ::: "memory"); \
                 __builtin_amdgcn_s_barrier(); \
                 __builtin_amdgcn_sched_barrier(0); }
#define SMFMA(bi, it) { \
        const unsigned short* Ac = As[bi]; \
        const unsigned short* Bc = Bs[bi]; \
        const bf16x8 fa0 = *(const bf16x8*)&Ac[(wm + l15) * 72 + aro]; \
        const bf16x8 fa1 = *(const bf16x8*)&Ac[(wm + 16 + l15) * 72 + aro]; \
        const bf16x8 fb  = *(const bf16x8*)&Bc[(wn + l15) * 72 + aro]; \
        const bf16x8 ga0 = *(const bf16x8*)&Ac[(wm + l15) * 72 + aro + 32]; \
        const bf16x8 ga1 = *(const bf16x8*)&Ac[(wm + 16 + l15) * 72 + aro + 32]; \
        const bf16x8 gb  = *(const bf16x8*)&Bc[(wn + l15) * 72 + aro + 32]; \
        if ((it) < 6) { \
            p00 = __builtin_amdgcn_mfma_f32_16x16x32_bf16(fa0, fb, p00, 0, 0, 0); \
            p01 = __builtin_amdgcn_mfma_f32_16x16x32_bf16(fa1, fb, p01, 0, 0, 0); \
            p00 = __builtin_amdgcn_mfma_f32_16x16x32_bf16(ga0, gb, p00, 0, 0, 0); \
            p01 = __builtin_amdgcn_mfma_f32_16x16x32_bf16(ga1, gb, p01, 0, 0, 0); \
        } else { \
            p10 = __builtin_amdgcn_mfma_f32_16x16x32_bf16(fa0, fb, p10, 0, 0, 0); \
            p11 = __builtin_amdgcn_mfma_f32_16x16x32_bf16(fa1, fb, p11, 0, 0, 0); \
            p10 = __builtin_amdgcn_mfma_f32_16x16x32_bf16(ga0, gb, p10, 0, 0, 0); \
            p11 = __builtin_amdgcn_mfma_f32_16x16x32_bf16(ga1, gb, p11, 0, 0, 0); \
        } }

    SGLOADP(0);
    SGLOADQ(1);
    SSWRITEP(0);

    #pragma unroll
    for (int it = 0; it < 12; it += 2) {
        SBAR();
        if (it + 2 < 12) SGLOADP(it + 2);
        SMFMA(0, it);
        SSWRITEQ(1);                     // counted vmcnt: waits step it+1 only
        SBAR();
        if (it + 3 < 12) SGLOADQ(it + 3);
        SMFMA(1, it + 1);
        if (it + 2 < 12) SSWRITEP(0);    // counted vmcnt: waits step it+2 only
    }

#undef KOA
#undef KOB
#undef SGLOADP
#undef SGLOADQ
#undef SSWRITEP
#undef SSWRITEQ
#undef SBAR
#undef SMFMA

    // park scores in LDS (alias over As): 2 planes of [64][33] fp32 = 16896 B
    __syncthreads();                     // all waves done reading As/Bs
    float* Sl = (float*)&As[0][0];
    const int col = wn + l15;            // 0..31
    #pragma unroll
    for (int mi = 0; mi < 2; ++mi) {
        #pragma unroll
        for (int r = 0; r < 4; ++r) {
            const int row = wm + mi * 16 + quad * 4 + r;
            Sl[row * 33 + col]           = mi ? p01[r] : p00[r];
            Sl[64 * 33 + row * 33 + col] = mi ? p11[r] : p10[r];
        }
    }
    // stage this bin's 32 segment counts
    const int bin = (batch << 7) | (((m0 >> 6) & 7) << 4) | (t0 >> 5);
    if (tid < 32) cbuf[tid] = counts2[(bin << 5) | tid];
    __syncthreads();

    // process this bin: 1024 candidate slots (32 segments x 32), 4 rounds
    const unsigned* mybins = bins + (bin << 10);
    const float lb0 = lin_b[0], lb1 = lin_b[1];
    float ce = 0.f;
    #pragma unroll
    for (int k = 0; k < 4; ++k) {
        const int si = k * 256 + tid;
        const int blkb = si >> 5;
        const int slot = si & 31;
        if (slot < cbuf[blkb]) {
            const unsigned rec = mybins[si];
            const int j   = rec & 0x1FFFF;
            const int lab = (rec >> 17) & 1;
            const int h6  = (rec >> 18) & 63;
            const int t5  = (rec >> 24) & 31;
            const int mh = m0 + h6;
            const int mt = batch * 512 + t0 + t5;
            const float2 hl = ((const float2*)hlin)[mh];
            const float2 tl = ((const float2*)tlin)[mt];
            const int so = h6 * 33 + t5;
            const float z0 = Sl[so]           + hl.x + tl.x + lb0;
            const float z1 = Sl[64 * 33 + so] + hl.y + tl.y + lb1;
            out[1 + 2 * (size_t)j] = z0;
            out[2 + 2 * (size_t)j] = z1;
            const float mx = fmaxf(z0, z1);
            const float mn = fminf(z0, z1);
            ce += mx + log1pf(expf(mn - mx)) - (lab ? z1 : z0);
        }
    }
    #pragma unroll
    for (int o = 32; o >= 1; o >>= 1) ce += __shfl_xor(ce, o, 64);
    if (lane == 0) wsum[wave] = ce;
    __syncthreads();
    if (tid == 0)
        atomicAdd(out, (wsum[0] + wsum[1] + wsum[2] + wsum[3]) * (1.0f / (float)RR));
}

// ---------------------------------------------------------------------------
extern "C" void kernel_launch(void* const* d_in, const int* in_sizes, int n_in,
                              void* d_out, int out_size, void* d_ws, size_t ws_size,
                              hipStream_t stream) {
    const float* hidden    = (const float*)d_in[0];
    const int*   ent_start = (const int*)d_in[1];
    const int*   ent_label = (const int*)d_in[2];
    const int*   rel_head  = (const int*)d_in[3];
    const int*   rel_tail  = (const int*)d_in[4];
    const int*   rel_label = (const int*)d_in[5];
    const float* emb       = (const float*)d_in[6];
    const float* head_W1   = (const float*)d_in[7];
    const float* head_b1   = (const float*)d_in[8];
    const float* head_W2   = (const float*)d_in[9];
    const float* head_b2   = (const float*)d_in[10];
    const float* tail_W1   = (const float*)d_in[11];
    const float* tail_b1   = (const float*)d_in[12];
    const float* tail_W2   = (const float*)d_in[13];
    const float* tail_b2   = (const float*)d_in[14];
    const float* bil_W     = (const float*)d_in[15];
    const float* lin_W     = (const float*)d_in[16];
    const float* lin_b     = (const float*)d_in[17];
    float* out = (float*)d_out;

    // Workspace carve-up (256B-aligned chunks)
    char* w = (char*)d_ws;
    auto carve = [&](size_t bytes) {
        char* p = w; w += (bytes + 255) & ~(size_t)255; return p;
    };
    unsigned short* Hbf  = (unsigned short*)carve((size_t)MM * 768 * 2);
    unsigned short* Y1bf = (unsigned short*)carve((size_t)MM * 1536 * 2);
    unsigned short* HTbf = (unsigned short*)carve((size_t)MM * 768 * 2);
    unsigned short* hWbf = (unsigned short*)carve((size_t)MM * 768 * 2);
    unsigned short* W1ht = (unsigned short*)carve((size_t)768 * 768 * 2);
    unsigned short* W1tt = (unsigned short*)carve((size_t)768 * 768 * 2);
    unsigned short* W2ht = (unsigned short*)carve((size_t)384 * 768 * 2);
    unsigned short* W2tt = (unsigned short*)carve((size_t)384 * 768 * 2);
    unsigned short* bW0t = (unsigned short*)carve((size_t)384 * 384 * 2);
    unsigned short* bW1t = (unsigned short*)carve((size_t)384 * 384 * 2);
    float*          embc = (float*)carve((size_t)3 * 1536 * 4);
    float*          hlin = (float*)carve(2048 * 4);
    float*          tlin = (float*)carve(2048 * 4);
    int*            counts2 = (int*)carve((size_t)256 * 32 * 4);
    unsigned*       bins = (unsigned*)carve((size_t)256 * 1024 * 4);

    // 1) W1 transpose + hidden gather + embc fold + zeroing
    prep<<<2201, 256, 0, stream>>>(
        head_W1, tail_W1, W1ht, W1tt,
        hidden, ent_start, emb, head_b1, tail_b1, Hbf, embc,
        hlin, tlin, out);

    // 2) layer1 (384 tiles) + W2/bil transposes (864) + rel binning (64)
    gemm1_plus<<<1312, 256, 0, stream>>>(
        Hbf, W1ht, W1tt, embc, ent_label, Y1bf,
        head_W2, tail_W2, bil_W, W2ht, W2tt, bW0t, bW1t,
        rel_head, rel_tail, rel_label, counts2, bins);

    // 3) layer2: HTbf = relu(Y1 @ [W2h|W2t] + b2), N=768 (Nh=384), K=768,
    //    tail half reads Y1 cols 768..; epilogue fuses lin_proj via atomics
    gemm_mfma<true, true, false, true, true>
        <<<dim3(12, 16), 256, 0, stream>>>(
        Y1bf, 1536, 768, W2ht, W2tt, 768, 384, head_b2, tail_b2,
        nullptr, nullptr, lin_W, hlin, tlin, 768, HTbf, 768);

    // 4) bilinear left product: hWbf = heads @ bil_W[o], N=768 (Nh=384), K=384
    gemm_mfma<false, false, false, true, false>
        <<<dim3(12, 16), 256, 0, stream>>>(
        HTbf, 768, 0, bW0t, bW1t, 384, 384, nullptr, nullptr,
        nullptr, nullptr, nullptr, nullptr, nullptr, 384, hWbf, 768);

    // 5) fused score + binned relation gather + CE
    score_rel<<<dim3(16, 16), 256, 0, stream>>>(
        hWbf, HTbf, hlin, tlin, lin_b,
        counts2, bins, out);
}